// Round 6
// baseline (439.362 us; speedup 1.0000x reference)
//
#include <hip/hip_runtime.h>

// Problem constants (match reference)
#define B_  16
#define T_  256
#define D_  64
#define H_  2
#define HS_ 32
#define HB_ 32
#define K_  10

// ---------------------------------------------------------------------------
// Kernel 1: pointwise projections a_, b_, seqs_ (conv1/conv2/W, kernel_size=1)
// written directly in split-head layout [HB][T][HS], plus a2 = ||a|| per row.
// grid = B*T blocks, 64 threads (one output feature each).
// ---------------------------------------------------------------------------
__global__ void proj_kernel(const float* __restrict__ seqs,
                            const float* __restrict__ c1w, const float* __restrict__ c1b,
                            const float* __restrict__ c2w, const float* __restrict__ c2b,
                            const float* __restrict__ Ww,  const float* __restrict__ Wb,
                            float* __restrict__ A, float* __restrict__ Bp,
                            float* __restrict__ Sp, float* __restrict__ a2) {
  int bt = blockIdx.x;            // b*256 + t
  int b  = bt >> 8;
  int t  = bt & 255;
  int e  = threadIdx.x;           // output feature 0..63
  __shared__ float srow[64];
  srow[e] = seqs[(size_t)bt * 64 + e];
  __syncthreads();
  float sa = c1b[e], sb = c2b[e], sw = Wb[e];
#pragma unroll 8
  for (int d = 0; d < 64; ++d) {
    float sv = srow[d];
    sa = fmaf(sv, c1w[e * 64 + d], sa);   // einsum 'btd,ed->bte'
    sb = fmaf(sv, c2w[e * 64 + d], sb);
    sw = fmaf(sv, Ww [e * 64 + d], sw);
  }
  int h = e >> 5, s = e & 31;
  int x = h * B_ + b;                       // split_heads: head-major
  size_t idx = ((size_t)x * T_ + t) * HS_ + s;
  A[idx] = sa; Bp[idx] = sb; Sp[idx] = sw;
  // ||a[x,t,:]|| : reduce sa^2 over the 32-lane half-wave
  float sq = sa * sa;
  for (int off = 1; off < 32; off <<= 1) sq += __shfl_xor(sq, off, 64);
  if (s == 0) a2[x * T_ + t] = sqrtf(sq);
}

// ---------------------------------------------------------------------------
// Kernel 2: raw_graph[x][i][j] for j<=i (upper triangle forced to 0, never
// reads ti there). One block per (b,i): both heads share the contiguous
// 64 KB ti row tm[b,i,:,:]. 256 threads; chunk c = j*2+h owns 128 B of ti.
// ---------------------------------------------------------------------------
__global__ __launch_bounds__(256)
void raw_kernel(const float* __restrict__ tm,
                const float* __restrict__ A, const float* __restrict__ Bp,
                const float* __restrict__ a2v, float* __restrict__ raw) {
  int bt = blockIdx.x;            // b*256 + i
  int bb = bt >> 8;
  int i  = bt & 255;
  int tid = threadIdx.x;
  __shared__ float a_l[64];       // a[x,i,:] for both heads: [h*32+s]
  __shared__ float a2_l[2];
  if (tid < 64) {
    int h = tid >> 5, s = tid & 31;
    a_l[tid] = A[(((size_t)(h * B_ + bb)) * T_ + i) * HS_ + s];
  }
  if (tid < 2) a2_l[tid] = a2v[(tid * B_ + bb) * T_ + i];
  __syncthreads();
  const float* tmrow = tm + (size_t)bt * T_ * D_;   // [256 j][64 d]
#pragma unroll
  for (int it = 0; it < 2; ++it) {
    int c = it * 256 + tid;       // 0..511
    int j = c >> 1, h = c & 1;
    float val = 0.0f;
    if (j <= i) {
      const float4* tptr = (const float4*)(tmrow + (size_t)j * 64 + h * 32);
      const float4* bptr = (const float4*)(Bp + (((size_t)(h * B_ + bb)) * T_ + j) * HS_);
      const float* al = a_l + h * 32;
      float dot_ab = 0.f, dot_ta = 0.f, btsum = 0.f;
#pragma unroll
      for (int q = 0; q < 8; ++q) {
        float4 tv = tptr[q];
        float4 bv = bptr[q];
        float a0 = al[q*4+0], a1 = al[q*4+1], a2e = al[q*4+2], a3 = al[q*4+3];
        dot_ab = fmaf(a0, bv.x, fmaf(a1, bv.y, fmaf(a2e, bv.z, fmaf(a3, bv.w, dot_ab))));
        dot_ta = fmaf(a0, tv.x, fmaf(a1, tv.y, fmaf(a2e, tv.z, fmaf(a3, tv.w, dot_ta))));
        float e0 = bv.x + tv.x, e1 = bv.y + tv.y, e2 = bv.z + tv.z, e3 = bv.w + tv.w;
        btsum = fmaf(e0, e0, fmaf(e1, e1, fmaf(e2, e2, fmaf(e3, e3, btsum))));
      }
      float bt2 = sqrtf(btsum);
      val = (dot_ab + dot_ta) / (a2_l[h] * bt2 + 1e-6f);
    }
    raw[(((size_t)(h * B_ + bb)) * T_ + i) * T_ + j] = val;
  }
}

// ---------------------------------------------------------------------------
// Kernel 3: exact top-K (K=10) per row, jax.lax.top_k tie-break (lower index
// wins on equal values). One wave (64 lanes) per row; each lane holds 4 vals.
// Key = (order-preserving u32 of float) << 32 | (255 - idx).
// Output: m1 one-hot bitmask, 8 u32 per row.
// ---------------------------------------------------------------------------
__global__ void topk_kernel(const float* __restrict__ raw, unsigned* __restrict__ m1) {
  int row  = blockIdx.x;          // x*256 + i
  int lane = threadIdx.x;
  const float* r = raw + (size_t)row * T_;
  unsigned long long key[4];
#pragma unroll
  for (int q = 0; q < 4; ++q) {
    int idx = q * 64 + lane;
    unsigned bits = __float_as_uint(r[idx]);
    unsigned u = (bits & 0x80000000u) ? ~bits : (bits | 0x80000000u);
    key[q] = ((unsigned long long)u << 32) | (unsigned)(255 - idx);
  }
  unsigned myword = 0;            // lane w<8 accumulates m1 word w
  for (int k = 0; k < K_; ++k) {
    unsigned long long m = key[0];
    if (key[1] > m) m = key[1];
    if (key[2] > m) m = key[2];
    if (key[3] > m) m = key[3];
    for (int off = 1; off < 64; off <<= 1) {
      unsigned long long o = __shfl_xor(m, off, 64);
      if (o > m) m = o;
    }
    int idx = 255 - (int)(m & 0xFFFFFFFFull);
    if ((idx & 63) == lane) key[idx >> 6] = 0ull;   // remove winner
    if (lane == (idx >> 5)) myword |= 1u << (idx & 31);
  }
  if (lane < 8) m1[(size_t)row * 8 + lane] = myword;
}

// ---------------------------------------------------------------------------
// Kernel 4: symmetric mask: mrow[x][i] = m1[x][i] | column i bits of m1[x].
// One block per x (head-batch); bit-matrix in LDS (8 KB).
// ---------------------------------------------------------------------------
__global__ void symmask_kernel(const unsigned* __restrict__ m1, unsigned* __restrict__ mrow) {
  int x = blockIdx.x;
  __shared__ unsigned lm[T_ * 8];
  int tid = threadIdx.x;          // 0..255
  const unsigned* src = m1 + (size_t)x * (T_ * 8);
  for (int k2 = tid; k2 < T_ * 8; k2 += 256) lm[k2] = src[k2];
  __syncthreads();
  int i = tid;
  int iw = i >> 5, ib = i & 31;
#pragma unroll
  for (int w = 0; w < 8; ++w) {
    unsigned out = lm[i * 8 + w];
    for (int j2 = 0; j2 < 32; ++j2) {
      int j = w * 32 + j2;
      out |= ((lm[j * 8 + iw] >> ib) & 1u) << j2;
    }
    mrow[((size_t)x * T_ + i) * 8 + w] = out;
  }
}

// ---------------------------------------------------------------------------
// Kernel 5: sparse gather. outputs[x,i,:] = sum_j w * seqs_[x,j,:],
// tio[x,i,:] = sum_j w * ti[x,i,j,:], w = raw[x,i,j] (0 above diag already).
// One wave per row. Lanes 0..31 carry s; upper half duplicates (same cache
// lines, negligible extra HBM). Writes in merged-head layout; tio -> d_out.
// ---------------------------------------------------------------------------
__global__ void gather_kernel(const float* __restrict__ raw, const unsigned* __restrict__ mrow,
                              const float* __restrict__ tm, const float* __restrict__ Sp,
                              float* __restrict__ outm, float* __restrict__ tiom) {
  int row = blockIdx.x;           // x*256 + i
  int x = row >> 8, i = row & 255;
  int h = x >> 4, bb = x & 15;
  int lane = threadIdx.x;
  int s = lane & 31;
  const float* tmrow = tm + (((size_t)bb * T_ + i) * T_) * D_ + h * 32;  // + j*64 + s
  const float* sprow = Sp + ((size_t)x * T_) * HS_;                      // + j*32 + s
  const float* rrow  = raw + (size_t)row * T_;
  const unsigned* mw = mrow + (size_t)row * 8;
  float acc_o = 0.f, acc_t = 0.f;
#pragma unroll
  for (int w = 0; w < 8; ++w) {
    unsigned bits = mw[w];
    while (bits) {
      int j2 = __ffs(bits) - 1;
      bits &= bits - 1;
      int j = w * 32 + j2;
      float wgt = rrow[j];        // uniform scalar load
      if (wgt != 0.0f) {
        acc_t = fmaf(wgt, tmrow[(size_t)j * 64 + s], acc_t);
        acc_o = fmaf(wgt, sprow[(size_t)j * 32 + s], acc_o);
      }
    }
  }
  if (lane < 32) {
    size_t oidx = (((size_t)bb * T_ + i) * D_) + h * 32 + s;  // merged heads
    outm[oidx] = acc_o;
    tiom[oidx] = acc_t;
  }
}

// ---------------------------------------------------------------------------
// Kernel 6: LayerNorm over D=64 of merged outputs -> d_out first half.
// ---------------------------------------------------------------------------
__global__ void ln_kernel(const float* __restrict__ outm,
                          const float* __restrict__ g, const float* __restrict__ bta,
                          float* __restrict__ out) {
  int bt = blockIdx.x;
  int d  = threadIdx.x;           // 0..63, one wave
  float v = outm[(size_t)bt * 64 + d];
  float mu = v;
  for (int off = 1; off < 64; off <<= 1) mu += __shfl_xor(mu, off, 64);
  mu *= (1.0f / 64.0f);
  float dv = v - mu;
  float var = dv * dv;
  for (int off = 1; off < 64; off <<= 1) var += __shfl_xor(var, off, 64);
  var *= (1.0f / 64.0f);
  out[(size_t)bt * 64 + d] = dv * (1.0f / sqrtf(var + 1e-8f)) * g[d] + bta[d];
}

// ---------------------------------------------------------------------------
extern "C" void kernel_launch(void* const* d_in, const int* in_sizes, int n_in,
                              void* d_out, int out_size, void* d_ws, size_t ws_size,
                              hipStream_t stream) {
  const float* seqs = (const float*)d_in[0];
  // d_in[1] attention_mask: deterministic ~tril, computed in-kernel as j>i
  const float* tm   = (const float*)d_in[2];
  const float* c1w  = (const float*)d_in[3];
  const float* c1b  = (const float*)d_in[4];
  const float* c2w  = (const float*)d_in[5];
  const float* c2b  = (const float*)d_in[6];
  const float* Ww   = (const float*)d_in[7];
  const float* Wb   = (const float*)d_in[8];
  const float* lng  = (const float*)d_in[9];
  const float* lnb  = (const float*)d_in[10];

  // Workspace layout (floats). Total ~12.6 MB.
  float* ws   = (float*)d_ws;
  float* A    = ws;                       //  262144  [HB][T][HS]
  float* Bp   = ws + 262144;              //  262144
  float* Sp   = ws + 524288;              //  262144
  float* a2   = ws + 786432;              //    8192  [HB][T]
  float* raw  = ws + 794624;              // 2097152  [HB][T][T]
  unsigned* m1   = (unsigned*)(ws + 2891776);  // 65536 u32
  unsigned* mrow = m1 + 65536;                 // 65536 u32
  float* outm = (float*)(mrow + 65536);        // 262144 merged outputs

  float* out0 = (float*)d_out;            // layer_norm(outputs) [B][T][D]
  float* tiom = out0 + (size_t)B_ * T_ * D_;   // tio [B][T][D]

  proj_kernel   <<<B_ * T_, 64,  0, stream>>>(seqs, c1w, c1b, c2w, c2b, Ww, Wb, A, Bp, Sp, a2);
  raw_kernel    <<<B_ * T_, 256, 0, stream>>>(tm, A, Bp, a2, raw);
  topk_kernel   <<<HB_ * T_, 64, 0, stream>>>(raw, m1);
  symmask_kernel<<<HB_, 256, 0, stream>>>(m1, mrow);
  gather_kernel <<<HB_ * T_, 64, 0, stream>>>(raw, mrow, tm, Sp, outm, tiom);
  ln_kernel     <<<B_ * T_, 64,  0, stream>>>(outm, lng, lnb, out0);
}

// Round 7
// 419.257 us; speedup vs baseline: 1.0480x; 1.0480x over previous
//
#include <hip/hip_runtime.h>

// Problem constants (match reference)
#define B_  16
#define T_  256
#define D_  64
#define H_  2
#define HS_ 32
#define HB_ 32
#define K_  10

// ---------------------------------------------------------------------------
// Kernel 1: pointwise projections a_, b_, seqs_ (conv1/conv2/W, kernel_size=1)
// written directly in split-head layout [HB][T][HS], plus a2 = ||a|| per row.
// grid = B*T blocks, 64 threads (one output feature each).
// ---------------------------------------------------------------------------
__global__ void proj_kernel(const float* __restrict__ seqs,
                            const float* __restrict__ c1w, const float* __restrict__ c1b,
                            const float* __restrict__ c2w, const float* __restrict__ c2b,
                            const float* __restrict__ Ww,  const float* __restrict__ Wb,
                            float* __restrict__ A, float* __restrict__ Bp,
                            float* __restrict__ Sp, float* __restrict__ a2) {
  int bt = blockIdx.x;            // b*256 + t
  int b  = bt >> 8;
  int t  = bt & 255;
  int e  = threadIdx.x;           // output feature 0..63
  __shared__ float srow[64];
  srow[e] = seqs[(size_t)bt * 64 + e];
  __syncthreads();
  float sa = c1b[e], sb = c2b[e], sw = Wb[e];
#pragma unroll 8
  for (int d = 0; d < 64; ++d) {
    float sv = srow[d];
    sa = fmaf(sv, c1w[e * 64 + d], sa);   // einsum 'btd,ed->bte'
    sb = fmaf(sv, c2w[e * 64 + d], sb);
    sw = fmaf(sv, Ww [e * 64 + d], sw);
  }
  int h = e >> 5, s = e & 31;
  int x = h * B_ + b;                       // split_heads: head-major
  size_t idx = ((size_t)x * T_ + t) * HS_ + s;
  A[idx] = sa; Bp[idx] = sb; Sp[idx] = sw;
  // ||a[x,t,:]|| : reduce sa^2 over the 32-lane half-wave
  float sq = sa * sa;
  for (int off = 1; off < 32; off <<= 1) sq += __shfl_xor(sq, off, 64);
  if (s == 0) a2[x * T_ + t] = sqrtf(sq);
}

// ---------------------------------------------------------------------------
// Kernel 2 (REWRITTEN, coalesced): raw_graph[x][i][j] for j<=i.
// One block per (b,i), 4 waves. Wave w owns j in {w*4+g + 16k}. Per wave-
// iteration, lane L reads tm float4 at tmrow + jt*64 + L*16 -> the wave
// fetches 1 KB CONTIGUOUS (4 consecutive j-rows). 16-lane group g owns
// j=jt+g; 8-lane subgroup owns head h. Sums finished by 3-step shfl_xor
// over the 8 lanes. j>i zeros written by a disjoint zero-pass (no barrier).
// ---------------------------------------------------------------------------
__global__ __launch_bounds__(256)
void raw_kernel(const float* __restrict__ tm,
                const float* __restrict__ A, const float* __restrict__ Bp,
                const float* __restrict__ a2v, float* __restrict__ raw) {
  int bt  = blockIdx.x;           // b*256 + i
  int bb  = bt >> 8;
  int i   = bt & 255;
  int tid = threadIdx.x;
  int wave = tid >> 6;            // 0..3
  int lane = tid & 63;
  int grp  = lane >> 4;           // 0..3: which j of the 4-row tile
  int l16  = lane & 15;           // 0..15: d-chunk (4 floats each)
  int h    = l16 >> 3;            // head: d<32 -> 0, d>=32 -> 1
  int s4   = (l16 & 7) * 4;       // s offset within head

  // Zero-pass: j = tid > i, both heads. Disjoint from compute writes.
  if (tid > i) {
    raw[((size_t)bb * T_ + i) * T_ + tid] = 0.0f;
    raw[((size_t)(B_ + bb) * T_ + i) * T_ + tid] = 0.0f;
  }

  // Per-lane registers: a fragment (4 floats at [h][s4..s4+3]) and ||a||.
  int x = h * B_ + bb;
  const float4 av = *(const float4*)(A + (((size_t)x * T_) + i) * HS_ + s4);
  const float a2h = a2v[x * T_ + i];

  const float* tmrow = tm + (size_t)bt * T_ * D_;        // [256 j][64 d]
  const float* bpl   = Bp + ((size_t)x * T_) * HS_ + s4; // + j*32
  float* rrow = raw + ((size_t)x * T_ + i) * T_;         // + j

  for (int jt = wave * 4; jt <= i; jt += 16) {
    // Coalesced: wave reads tm rows [jt, jt+3] as 1 KB contiguous.
    float4 tv = ((const float4*)(tmrow + (size_t)jt * 64))[lane];
    int j = jt + grp;             // j <= 255 always (jt <= i <= 255, grp from lane)
    float4 bv = *(const float4*)(bpl + (size_t)j * 32);

    // Partials over this lane's 4 d's.
    float pnum = av.x * bv.x + av.y * bv.y + av.z * bv.z + av.w * bv.w
               + av.x * tv.x + av.y * tv.y + av.z * tv.z + av.w * tv.w;
    float e0 = bv.x + tv.x, e1 = bv.y + tv.y, e2 = bv.z + tv.z, e3 = bv.w + tv.w;
    float pbt = fmaf(e0, e0, fmaf(e1, e1, fmaf(e2, e2, e3 * e3)));

    // Reduce over the 8 lanes of this (j,h) subgroup.
    pnum += __shfl_xor(pnum, 1, 64); pbt += __shfl_xor(pbt, 1, 64);
    pnum += __shfl_xor(pnum, 2, 64); pbt += __shfl_xor(pbt, 2, 64);
    pnum += __shfl_xor(pnum, 4, 64); pbt += __shfl_xor(pbt, 4, 64);

    if ((l16 & 7) == 0 && j <= i) {
      rrow[j] = pnum / (a2h * sqrtf(pbt) + 1e-6f);
    }
  }
}

// ---------------------------------------------------------------------------
// Kernel 3: exact top-K (K=10) per row, jax.lax.top_k tie-break (lower index
// wins on equal values). One wave (64 lanes) per row; each lane holds 4 vals.
// Key = (order-preserving u32 of float) << 32 | (255 - idx).
// Output: m1 one-hot bitmask, 8 u32 per row.
// ---------------------------------------------------------------------------
__global__ void topk_kernel(const float* __restrict__ raw, unsigned* __restrict__ m1) {
  int row  = blockIdx.x;          // x*256 + i
  int lane = threadIdx.x;
  const float* r = raw + (size_t)row * T_;
  unsigned long long key[4];
#pragma unroll
  for (int q = 0; q < 4; ++q) {
    int idx = q * 64 + lane;
    unsigned bits = __float_as_uint(r[idx]);
    unsigned u = (bits & 0x80000000u) ? ~bits : (bits | 0x80000000u);
    key[q] = ((unsigned long long)u << 32) | (unsigned)(255 - idx);
  }
  unsigned myword = 0;            // lane w<8 accumulates m1 word w
  for (int k = 0; k < K_; ++k) {
    unsigned long long m = key[0];
    if (key[1] > m) m = key[1];
    if (key[2] > m) m = key[2];
    if (key[3] > m) m = key[3];
    for (int off = 1; off < 64; off <<= 1) {
      unsigned long long o = __shfl_xor(m, off, 64);
      if (o > m) m = o;
    }
    int idx = 255 - (int)(m & 0xFFFFFFFFull);
    if ((idx & 63) == lane) key[idx >> 6] = 0ull;   // remove winner
    if (lane == (idx >> 5)) myword |= 1u << (idx & 31);
  }
  if (lane < 8) m1[(size_t)row * 8 + lane] = myword;
}

// ---------------------------------------------------------------------------
// Kernel 4: symmetric mask: mrow[x][i] = m1[x][i] | column i bits of m1[x].
// One block per x (head-batch); bit-matrix in LDS (8 KB).
// ---------------------------------------------------------------------------
__global__ void symmask_kernel(const unsigned* __restrict__ m1, unsigned* __restrict__ mrow) {
  int x = blockIdx.x;
  __shared__ unsigned lm[T_ * 8];
  int tid = threadIdx.x;          // 0..255
  const unsigned* src = m1 + (size_t)x * (T_ * 8);
  for (int k2 = tid; k2 < T_ * 8; k2 += 256) lm[k2] = src[k2];
  __syncthreads();
  int i = tid;
  int iw = i >> 5, ib = i & 31;
#pragma unroll
  for (int w = 0; w < 8; ++w) {
    unsigned out = lm[i * 8 + w];
    for (int j2 = 0; j2 < 32; ++j2) {
      int j = w * 32 + j2;
      out |= ((lm[j * 8 + iw] >> ib) & 1u) << j2;
    }
    mrow[((size_t)x * T_ + i) * 8 + w] = out;
  }
}

// ---------------------------------------------------------------------------
// Kernel 5: sparse gather. outputs[x,i,:] = sum_j w * seqs_[x,j,:],
// tio[x,i,:] = sum_j w * ti[x,i,j,:], w = raw[x,i,j] (0 above diag already).
// One wave per row. Lanes 0..31 carry s; upper half duplicates (same cache
// lines, negligible extra HBM). Writes in merged-head layout; tio -> d_out.
// ---------------------------------------------------------------------------
__global__ void gather_kernel(const float* __restrict__ raw, const unsigned* __restrict__ mrow,
                              const float* __restrict__ tm, const float* __restrict__ Sp,
                              float* __restrict__ outm, float* __restrict__ tiom) {
  int row = blockIdx.x;           // x*256 + i
  int x = row >> 8, i = row & 255;
  int h = x >> 4, bb = x & 15;
  int lane = threadIdx.x;
  int s = lane & 31;
  const float* tmrow = tm + (((size_t)bb * T_ + i) * T_) * D_ + h * 32;  // + j*64 + s
  const float* sprow = Sp + ((size_t)x * T_) * HS_;                      // + j*32 + s
  const float* rrow  = raw + (size_t)row * T_;
  const unsigned* mw = mrow + (size_t)row * 8;
  float acc_o = 0.f, acc_t = 0.f;
#pragma unroll
  for (int w = 0; w < 8; ++w) {
    unsigned bits = mw[w];
    while (bits) {
      int j2 = __ffs(bits) - 1;
      bits &= bits - 1;
      int j = w * 32 + j2;
      float wgt = rrow[j];        // uniform scalar load
      if (wgt != 0.0f) {
        acc_t = fmaf(wgt, tmrow[(size_t)j * 64 + s], acc_t);
        acc_o = fmaf(wgt, sprow[(size_t)j * 32 + s], acc_o);
      }
    }
  }
  if (lane < 32) {
    size_t oidx = (((size_t)bb * T_ + i) * D_) + h * 32 + s;  // merged heads
    outm[oidx] = acc_o;
    tiom[oidx] = acc_t;
  }
}

// ---------------------------------------------------------------------------
// Kernel 6: LayerNorm over D=64 of merged outputs -> d_out first half.
// ---------------------------------------------------------------------------
__global__ void ln_kernel(const float* __restrict__ outm,
                          const float* __restrict__ g, const float* __restrict__ bta,
                          float* __restrict__ out) {
  int bt = blockIdx.x;
  int d  = threadIdx.x;           // 0..63, one wave
  float v = outm[(size_t)bt * 64 + d];
  float mu = v;
  for (int off = 1; off < 64; off <<= 1) mu += __shfl_xor(mu, off, 64);
  mu *= (1.0f / 64.0f);
  float dv = v - mu;
  float var = dv * dv;
  for (int off = 1; off < 64; off <<= 1) var += __shfl_xor(var, off, 64);
  var *= (1.0f / 64.0f);
  out[(size_t)bt * 64 + d] = dv * (1.0f / sqrtf(var + 1e-8f)) * g[d] + bta[d];
}

// ---------------------------------------------------------------------------
extern "C" void kernel_launch(void* const* d_in, const int* in_sizes, int n_in,
                              void* d_out, int out_size, void* d_ws, size_t ws_size,
                              hipStream_t stream) {
  const float* seqs = (const float*)d_in[0];
  // d_in[1] attention_mask: deterministic ~tril, computed in-kernel as j>i
  const float* tm   = (const float*)d_in[2];
  const float* c1w  = (const float*)d_in[3];
  const float* c1b  = (const float*)d_in[4];
  const float* c2w  = (const float*)d_in[5];
  const float* c2b  = (const float*)d_in[6];
  const float* Ww   = (const float*)d_in[7];
  const float* Wb   = (const float*)d_in[8];
  const float* lng  = (const float*)d_in[9];
  const float* lnb  = (const float*)d_in[10];

  // Workspace layout (floats). Total ~12.6 MB.
  float* ws   = (float*)d_ws;
  float* A    = ws;                       //  262144  [HB][T][HS]
  float* Bp   = ws + 262144;              //  262144
  float* Sp   = ws + 524288;              //  262144
  float* a2   = ws + 786432;              //    8192  [HB][T]
  float* raw  = ws + 794624;              // 2097152  [HB][T][T]
  unsigned* m1   = (unsigned*)(ws + 2891776);  // 65536 u32
  unsigned* mrow = m1 + 65536;                 // 65536 u32
  float* outm = (float*)(mrow + 65536);        // 262144 merged outputs

  float* out0 = (float*)d_out;            // layer_norm(outputs) [B][T][D]
  float* tiom = out0 + (size_t)B_ * T_ * D_;   // tio [B][T][D]

  proj_kernel   <<<B_ * T_, 64,  0, stream>>>(seqs, c1w, c1b, c2w, c2b, Ww, Wb, A, Bp, Sp, a2);
  raw_kernel    <<<B_ * T_, 256, 0, stream>>>(tm, A, Bp, a2, raw);
  topk_kernel   <<<HB_ * T_, 64, 0, stream>>>(raw, m1);
  symmask_kernel<<<HB_, 256, 0, stream>>>(m1, mrow);
  gather_kernel <<<HB_ * T_, 64, 0, stream>>>(raw, mrow, tm, Sp, outm, tiom);
  ln_kernel     <<<B_ * T_, 64,  0, stream>>>(outm, lng, lnb, out0);
}